// Round 2
// baseline (106.143 us; speedup 1.0000x reference)
//
#include <hip/hip_runtime.h>

// BatchWiseTripletLoss: n=8192 rows, d=128, scalar output.
// K1 normalize->bf16 ws; K2 MFMA pass computing per-row max_neg/max_pos
// (partials over SPLIT column ranges x 2 column-half waves); K3 combine
// maxima; K4 MFMA pass accumulating thresholded loss; K5 final reduce.

#define D 128
#define BM 128
#define BN 128
#define SPLIT 8
#define NPART (SPLIT * 2)  // blockIdx.y x wc column-half partials
#define MARGIN 0.1f
#define NEG_FLOOR 0.6f
#define NINF -1e30f

typedef short bf16x8 __attribute__((ext_vector_type(8)));
typedef float f32x4 __attribute__((ext_vector_type(4)));

__device__ __forceinline__ unsigned short f2bf(float f) {
  unsigned u = __float_as_uint(f);
  u += 0x7FFFu + ((u >> 16) & 1u);
  return (unsigned short)(u >> 16);
}

// ---- K1: L2-normalize rows, emit bf16 ----
__global__ void k_normalize(const float* __restrict__ emb,
                            unsigned short* __restrict__ eb, int n) {
  int wave = threadIdx.x >> 6;
  int lane = threadIdx.x & 63;
  int row = blockIdx.x * 4 + wave;
  if (row >= n) return;
  float2 v = *(const float2*)(emb + (size_t)row * D + lane * 2);
  float ss = v.x * v.x + v.y * v.y;
#pragma unroll
  for (int off = 1; off < 64; off <<= 1) ss += __shfl_xor(ss, off, 64);
  float inv = 1.0f / fmaxf(sqrtf(ss), 1e-12f);
  unsigned short a = f2bf(v.x * inv);
  unsigned short b = f2bf(v.y * inv);
  *(unsigned int*)(eb + (size_t)row * D + lane * 2) =
      (unsigned)a | ((unsigned)b << 16);
}

// ---- K2/K4: GEMM pass with fused epilogue ----
// PASS 0: running max_neg / max_pos per row -> partials [NPART][n]
// PASS 1: thresholded loss sums per row     -> partials [NPART][n]
template <int PASS>
__global__ __launch_bounds__(256, 2) void k_pass(
    const unsigned short* __restrict__ eb, const int* __restrict__ tgt,
    float* __restrict__ mneg_p, float* __restrict__ mpos_p,
    const float* __restrict__ fneg, const float* __restrict__ fpos,
    float* __restrict__ loss_p, int n) {
  __shared__ char Bs[BN * 256];  // 128 rows x 128 bf16 (256B), chunk-swizzled

  const int tid = threadIdx.x;
  const int lane = tid & 63;
  const int w = tid >> 6;
  const int wr = w >> 1, wc = w & 1;
  const int l15 = lane & 15, g = lane >> 4;

  const int m0 = blockIdx.x * BM;
  const int colsPer = n / SPLIT;
  const int c0base = blockIdx.y * colsPer;
  const int pidx = blockIdx.y * 2 + wc;  // per-column-half partial slot

  // A fragments: this wave's 64 rows x K=128, plus row targets.
  bf16x8 a[4][4];
  int tr[4][4];
#pragma unroll
  for (int mt = 0; mt < 4; ++mt) {
    int rowA = m0 + wr * 64 + mt * 16 + l15;
#pragma unroll
    for (int ks = 0; ks < 4; ++ks)
      a[mt][ks] = *(const bf16x8*)(eb + (size_t)rowA * D + ks * 32 + g * 8);
    int rowT = m0 + wr * 64 + mt * 16 + g * 4;
#pragma unroll
    for (int r = 0; r < 4; ++r) tr[mt][r] = tgt[rowT + r];
  }

  float accN[4][4], accP[4][4], lossAcc[4][4];
  if (PASS == 0) {
#pragma unroll
    for (int mt = 0; mt < 4; ++mt)
#pragma unroll
      for (int r = 0; r < 4; ++r) {
        accN[mt][r] = NINF;
        accP[mt][r] = NINF;
      }
  } else {
#pragma unroll
    for (int mt = 0; mt < 4; ++mt) {
      int rowT = m0 + wr * 64 + mt * 16 + g * 4;
#pragma unroll
      for (int r = 0; r < 4; ++r) {
        accN[mt][r] = fneg[rowT + r] + MARGIN;                    // thr_pos
        accP[mt][r] = fmaxf(NEG_FLOOR, fpos[rowT + r]) - MARGIN;  // thr_neg
        lossAcc[mt][r] = 0.0f;
      }
    }
  }

  bool diagElem[4];
#pragma unroll
  for (int r = 0; r < 4; ++r) diagElem[r] = (g * 4 + r) == l15;

  const int nIter = colsPer / BN;
  for (int it = 0; it < nIter; ++it) {
    const int c0 = c0base + it * BN;
    // Stage B tile (rows c0..c0+127). Linear LDS dest + inverse-swizzled
    // global source; reads below apply the same XOR (involution).
#pragma unroll
    for (int i = 0; i < 8; ++i) {
      int ldsOff = i * 4096 + tid * 16;
      int r = i * 16 + (tid >> 4);
      int csrc = (tid & 15) ^ (r & 7);
      const unsigned short* src = eb + (size_t)(c0 + r) * D + csrc * 8;
      __builtin_amdgcn_global_load_lds(
          (const __attribute__((address_space(1))) void*)src,
          (__attribute__((address_space(3))) void*)(Bs + ldsOff), 16, 0, 0);
    }
    __syncthreads();

#pragma unroll
    for (int nt = 0; nt < 4; ++nt) {
      f32x4 acc[4];
#pragma unroll
      for (int mt = 0; mt < 4; ++mt) acc[mt] = (f32x4){0.f, 0.f, 0.f, 0.f};
      const int lrow = wc * 64 + nt * 16 + l15;
#pragma unroll
      for (int ks = 0; ks < 4; ++ks) {
        int chunk = (ks * 4 + g) ^ (lrow & 7);
        bf16x8 b = *(const bf16x8*)(Bs + lrow * 256 + chunk * 16);
#pragma unroll
        for (int mt = 0; mt < 4; ++mt)
          acc[mt] = __builtin_amdgcn_mfma_f32_16x16x32_bf16(a[mt][ks], b,
                                                            acc[mt], 0, 0, 0);
      }
      // Fused epilogue for this 64x16 column stripe.
      int colg = c0 + wc * 64 + nt * 16 + l15;
      int tc = tgt[colg];
      int colTileBase = colg - l15;
#pragma unroll
      for (int mt = 0; mt < 4; ++mt) {
        int rowTileBase = m0 + wr * 64 + mt * 16;
        bool diagTile = (rowTileBase == colTileBase);
#pragma unroll
        for (int r = 0; r < 4; ++r) {
          float s = acc[mt][r];
          bool same = (tr[mt][r] == tc);
          bool posOk = same && !(diagTile && diagElem[r]);
          if (PASS == 0) {
            accN[mt][r] = fmaxf(accN[mt][r], same ? NINF : s);
            accP[mt][r] = fmaxf(accP[mt][r], posOk ? s : NINF);
          } else {
            float v1 = (posOk && s < accN[mt][r]) ? (1.0f - s) : 0.0f;
            float v2 = (!same && s > accP[mt][r]) ? s : 0.0f;
            lossAcc[mt][r] += v1 + v2;
          }
        }
      }
    }
    __syncthreads();
  }

  // Cross-lane reduce over the 16 lanes sharing each row (lane bits 0..3).
#pragma unroll
  for (int mt = 0; mt < 4; ++mt) {
#pragma unroll
    for (int r = 0; r < 4; ++r) {
      int row = m0 + wr * 64 + mt * 16 + g * 4 + r;
      if (PASS == 0) {
        float vn = accN[mt][r], vp = accP[mt][r];
#pragma unroll
        for (int off = 1; off < 16; off <<= 1) {
          vn = fmaxf(vn, __shfl_xor(vn, off, 64));
          vp = fmaxf(vp, __shfl_xor(vp, off, 64));
        }
        if (l15 == 0) {
          mneg_p[(size_t)pidx * n + row] = vn;
          mpos_p[(size_t)pidx * n + row] = vp;
        }
      } else {
        float vl = lossAcc[mt][r];
#pragma unroll
        for (int off = 1; off < 16; off <<= 1) vl += __shfl_xor(vl, off, 64);
        if (l15 == 0) loss_p[(size_t)pidx * n + row] = vl;
      }
    }
  }
}

// ---- K3: combine NPART partial maxima ----
__global__ void k_combine(const float* __restrict__ mneg_p,
                          const float* __restrict__ mpos_p,
                          float* __restrict__ fneg, float* __restrict__ fpos,
                          int n) {
  int i = blockIdx.x * blockDim.x + threadIdx.x;
  if (i >= n) return;
  float vn = NINF, vp = NINF;
#pragma unroll
  for (int s = 0; s < NPART; ++s) {
    vn = fmaxf(vn, mneg_p[(size_t)s * n + i]);
    vp = fmaxf(vp, mpos_p[(size_t)s * n + i]);
  }
  fneg[i] = vn;
  fpos[i] = vp;
}

// ---- K5: deterministic final reduction ----
__global__ void k_final(const float* __restrict__ loss_p,
                        const float* __restrict__ fpos,
                        float* __restrict__ out, int n) {
  __shared__ float red[1024];
  float acc = 0.f;
  for (int i = threadIdx.x; i < n; i += 1024) {
    if (fpos[i] > -1e29f) {  // has_pos
      float s = 0.f;
#pragma unroll
      for (int sp = 0; sp < NPART; ++sp) s += loss_p[(size_t)sp * n + i];
      acc += s;
    }
  }
  red[threadIdx.x] = acc;
  __syncthreads();
  for (int off = 512; off > 0; off >>= 1) {
    if ((int)threadIdx.x < off) red[threadIdx.x] += red[threadIdx.x + off];
    __syncthreads();
  }
  if (threadIdx.x == 0) out[0] = red[0] / (float)n;
}

extern "C" void kernel_launch(void* const* d_in, const int* in_sizes, int n_in,
                              void* d_out, int out_size, void* d_ws,
                              size_t ws_size, hipStream_t stream) {
  const float* emb = (const float*)d_in[0];
  const int* tgt = (const int*)d_in[1];
  float* out = (float*)d_out;
  const int n = in_sizes[1];  // 8192

  char* ws = (char*)d_ws;
  unsigned short* eb = (unsigned short*)ws;  // bf16 normalized [n][128]
  size_t ebBytes = (size_t)n * D * sizeof(unsigned short);
  float* mneg_p = (float*)(ws + ebBytes);       // [NPART][n]
  float* mpos_p = mneg_p + (size_t)NPART * n;   // [NPART][n]
  float* loss_p = mpos_p + (size_t)NPART * n;   // [NPART][n]
  float* fneg = loss_p + (size_t)NPART * n;     // [n]
  float* fpos = fneg + n;                       // [n]

  k_normalize<<<n / 4, 256, 0, stream>>>(emb, eb, n);

  dim3 grid(n / BM, SPLIT);
  k_pass<0><<<grid, 256, 0, stream>>>(eb, tgt, mneg_p, mpos_p, fneg, fpos,
                                      loss_p, n);
  k_combine<<<(n + 255) / 256, 256, 0, stream>>>(mneg_p, mpos_p, fneg, fpos,
                                                 n);
  k_pass<1><<<grid, 256, 0, stream>>>(eb, tgt, mneg_p, mpos_p, fneg, fpos,
                                      loss_p, n);
  k_final<<<1, 1024, 0, stream>>>(loss_p, fpos, out, n);
}